// Round 2
// baseline (807.552 us; speedup 1.0000x reference)
//
#include <hip/hip_runtime.h>

#define N_NODES 50000
#define N_ENT   100000
#define N_REL   16
#define DIM     128
#define E_EDGES 600000
#define NQ      8192
#define PATH_DIM 5
#define NK      (N_NODES * N_REL)        /* 800000 (dst,rel) segments */
#define KTOT    (N_REL * DIM + DIM)      /* 2176 = 16 rel slots + self slot */
#define NBLK_SEG (NK / 256)              /* 3125 */

typedef __attribute__((ext_vector_type(8))) short short8;
typedef __attribute__((ext_vector_type(4))) float floatx4;

static __device__ __forceinline__ short f2bf(float x) {
  unsigned u = __builtin_bit_cast(unsigned, x);
  u = (u + 0x7FFFu + ((u >> 16) & 1u)) >> 16;   // RNE
  return (short)u;
}

static __device__ __forceinline__ int wave_incl_scan(int x) {
  int lane = threadIdx.x & 63;
  #pragma unroll
  for (int off = 1; off < 64; off <<= 1) {
    int y = __shfl_up(x, off, 64);
    if (lane >= off) x += y;
  }
  return x;
}

// ---------- edge sort by (dst*16 + etype): hist -> scan -> scatter ----------
__global__ void k_hist(const int* __restrict__ ei, const int* __restrict__ et,
                       int* __restrict__ hist) {
  int e = blockIdx.x * 256 + threadIdx.x;
  if (e >= E_EDGES) return;
  int key = ei[E_EDGES + e] * N_REL + et[e];
  atomicAdd(&hist[key], 1);
}

__global__ void k_bsum(const int* __restrict__ hist, int* __restrict__ bsum) {
  int t = threadIdx.x;
  int v = hist[blockIdx.x * 256 + t];
  #pragma unroll
  for (int off = 32; off; off >>= 1) v += __shfl_xor(v, off, 64);
  __shared__ int s4[4];
  if ((t & 63) == 0) s4[t >> 6] = v;
  __syncthreads();
  if (t == 0) bsum[blockIdx.x] = s4[0] + s4[1] + s4[2] + s4[3];
}

__global__ void k_bscan(int* __restrict__ bsum) {   // 1 block, 1024 threads, 3125 items
  int t = threadIdx.x;
  int v[4], loc[4], s = 0;
  #pragma unroll
  for (int i = 0; i < 4; i++) {
    int idx = t * 4 + i;
    v[i] = (idx < NBLK_SEG) ? bsum[idx] : 0;
    loc[i] = s; s += v[i];
  }
  int incl = wave_incl_scan(s);
  __shared__ int wsum[16];
  int wid = t >> 6, lane = t & 63;
  if (lane == 63) wsum[wid] = incl;
  __syncthreads();
  if (t < 16) {
    int x = wsum[t];
    #pragma unroll
    for (int off = 1; off < 16; off <<= 1) {
      int y = __shfl_up(x, off, 64);
      if (t >= off) x += y;
    }
    wsum[t] = x;
  }
  __syncthreads();
  int wexcl = wid ? wsum[wid - 1] : 0;
  int texcl = wexcl + incl - s;
  #pragma unroll
  for (int i = 0; i < 4; i++) {
    int idx = t * 4 + i;
    if (idx < NBLK_SEG) bsum[idx] = texcl + loc[i];
  }
}

__global__ void k_offsets(const int* __restrict__ hist, const int* __restrict__ bsum,
                          int* __restrict__ offs, int* __restrict__ cursor) {
  int t = threadIdx.x;
  int g = blockIdx.x * 256 + t;
  int v = hist[g];
  int incl = wave_incl_scan(v);
  __shared__ int wsum[4];
  int wid = t >> 6, lane = t & 63;
  if (lane == 63) wsum[wid] = incl;
  __syncthreads();
  int wexcl = 0;
  for (int i = 0; i < wid; i++) wexcl += wsum[i];
  int off = bsum[blockIdx.x] + wexcl + incl - v;
  offs[g] = off;
  cursor[g] = off;
  if (g == NK - 1) offs[NK] = off + v;
}

__global__ void k_scatter(const int* __restrict__ ei, const int* __restrict__ et,
                          int* __restrict__ cursor, int* __restrict__ ssrc) {
  int e = blockIdx.x * 256 + threadIdx.x;
  if (e >= E_EDGES) return;
  int src = ei[e];
  int key = ei[E_EDGES + e] * N_REL + et[e];
  int pos = atomicAdd(&cursor[key], 1);
  ssrc[pos] = src;
}

// ---------- h0 gather ----------
__global__ void k_h0(const int* __restrict__ nid, const float* __restrict__ emb,
                     float* __restrict__ h) {
  int g = blockIdx.x * 256 + threadIdx.x;     // over N*DIM/4
  int n = g >> 5;
  int d4 = (g & 31) * 4;
  float4 v = *(const float4*)(emb + (size_t)nid[n] * DIM + d4);
  *(float4*)(h + (size_t)n * DIM + d4) = v;
}

// ---------- W_cat bf16, layout [layer][n=out 128][k=2176 (16 rel slots | self)] ----------
__global__ void k_wcat(const float* __restrict__ wrel, const float* __restrict__ wself,
                       short* __restrict__ wcat) {
  int g = blockIdx.x * 256 + threadIdx.x;
  if (g >= 2 * DIM * KTOT) return;
  int l = g / (DIM * KTOT);
  int rem = g - l * DIM * KTOT;
  int n = rem / KTOT;
  int k = rem - n * KTOT;
  float v;
  if (k < N_REL * DIM) {
    int r = k >> 7, d = k & 127;
    v = wrel[(((size_t)l * N_REL + r) * DIM + d) * DIM + n];
  } else {
    int d = k - N_REL * DIM;
    v = wself[((size_t)l * DIM + d) * DIM + n];
  }
  wcat[g] = f2bf(v);
}

// ---------- self slot copy h -> m[:, selfoff:selfoff+128] ----------
__global__ void k_selfcopy(const float* __restrict__ h, short* __restrict__ m,
                           int mw, int selfoff) {
  int g = blockIdx.x * 256 + threadIdx.x;   // over N*64
  int n = g >> 6;
  int d2 = (g & 63) * 2;
  float2 v = *(const float2*)(h + (size_t)n * DIM + d2);
  unsigned pk = (unsigned)(unsigned short)f2bf(v.x) |
                ((unsigned)(unsigned short)f2bf(v.y) << 16);
  *(unsigned*)(m + (size_t)n * mw + selfoff + d2) = pk;
}

// ---------- per-(dst,rel) mean for a relation chunk: one wave per segment ----------
__global__ void k_mean(const float* __restrict__ h, const int* __restrict__ offs,
                       const int* __restrict__ ssrc, short* __restrict__ m,
                       int mw, int rbase, int glog2) {
  int s = (blockIdx.x * 256 + threadIdx.x) >> 6;   // local segment id, wave-uniform
  int lane = threadIdx.x & 63;
  int dst = s >> glog2;
  int rr = s & ((1 << glog2) - 1);
  int key = dst * N_REL + rbase + rr;
  int start = offs[key], end = offs[key + 1];
  float s0 = 0.f, s1 = 0.f;
  for (int p = start; p < end; ++p) {
    int src = ssrc[p];
    float2 v = *(const float2*)(h + (size_t)src * DIM + lane * 2);
    s0 += v.x; s1 += v.y;
  }
  int cnt = end - start;
  float inv = 1.0f / (float)(cnt > 0 ? cnt : 1);
  unsigned pk = (unsigned)(unsigned short)f2bf(s0 * inv) |
                ((unsigned)(unsigned short)f2bf(s1 * inv) << 16);
  *(unsigned*)(m + (size_t)dst * mw + rr * DIM + lane * 2) = pk;
}

// ---------- chunk GEMM: C[=hout] (+)= m[N,kc] @ wb^T, optional relu ----------
template <bool ACC, bool RELU>
__global__ __launch_bounds__(256) void k_gemm(const short* __restrict__ m, int mw,
                                              const short* __restrict__ wb, int kc,
                                              float* __restrict__ hout) {
  __shared__ short As[128][40];   // +8 pad: row stride 80B -> 2-way bank alias (free)
  __shared__ short Bs[128][40];   // B stored [n][k]
  int t = threadIdx.x;
  int wave = t >> 6, lane = t & 63;
  int quad = lane >> 4, rA = lane & 15;
  int row0 = blockIdx.x * 128;
  floatx4 acc[2][8];
  #pragma unroll
  for (int a = 0; a < 2; a++)
    #pragma unroll
    for (int b = 0; b < 8; b++) acc[a][b] = (floatx4)0.f;

  for (int k0 = 0; k0 < kc; k0 += 32) {
    __syncthreads();
    #pragma unroll
    for (int it = 0; it < 2; it++) {
      int idx = t + it * 256;
      int r = idx >> 2, q = idx & 3;
      int grow = row0 + r;
      uint4 va = (grow < N_NODES)
                   ? *(const uint4*)(m + (size_t)grow * mw + k0 + q * 8)
                   : make_uint4(0u, 0u, 0u, 0u);
      *(uint4*)&As[r][q * 8] = va;
      uint4 vb = *(const uint4*)(wb + (size_t)r * KTOT + k0 + q * 8);
      *(uint4*)&Bs[r][q * 8] = vb;
    }
    __syncthreads();
    short8 a0 = *(const short8*)&As[wave * 32 + rA][quad * 8];
    short8 a1 = *(const short8*)&As[wave * 32 + 16 + rA][quad * 8];
    #pragma unroll
    for (int nt = 0; nt < 8; nt++) {
      short8 b = *(const short8*)&Bs[nt * 16 + rA][quad * 8];
      acc[0][nt] = __builtin_amdgcn_mfma_f32_16x16x32_bf16(a0, b, acc[0][nt], 0, 0, 0);
      acc[1][nt] = __builtin_amdgcn_mfma_f32_16x16x32_bf16(a1, b, acc[1][nt], 0, 0, 0);
    }
  }
  #pragma unroll
  for (int mt = 0; mt < 2; mt++)
    #pragma unroll
    for (int nt = 0; nt < 8; nt++)
      #pragma unroll
      for (int j = 0; j < 4; j++) {
        int row = row0 + wave * 32 + mt * 16 + quad * 4 + j;  // C: row=(lane>>4)*4+reg
        int col = nt * 16 + rA;                                // C: col=lane&15
        if (row < N_NODES) {
          size_t o = (size_t)row * DIM + col;
          float v = acc[mt][nt][j];
          if (ACC) v += hout[o];
          if (RELU) v = fmaxf(v, 0.f);
          hout[o] = v;
        }
      }
}

// ---------- scoring ----------
__global__ void k_score(const float* __restrict__ h, const int* __restrict__ heads,
                        const int* __restrict__ rels, const int* __restrict__ tails,
                        const float* __restrict__ rel_emb, const float* __restrict__ path_feat,
                        const int* __restrict__ task_idx, const float* __restrict__ delta_w,
                        const float* __restrict__ lambda_logit, const float* __restrict__ rule_init,
                        float* __restrict__ out) {
  int q = (blockIdx.x * 256 + threadIdx.x) >> 6;
  int lane = threadIdx.x & 63;
  int hd = heads[q], tl = tails[q], rl = rels[q];
  float2 a = *(const float2*)(h + (size_t)hd * DIM + lane * 2);
  float2 r = *(const float2*)(rel_emb + (size_t)rl * DIM + lane * 2);
  float2 c = *(const float2*)(h + (size_t)tl * DIM + lane * 2);
  float s = a.x * r.x * c.x + a.y * r.y * c.y;
  #pragma unroll
  for (int off = 32; off; off >>= 1) s += __shfl_xor(s, off, 64);
  if (lane == 0) {
    int task = task_idx[0];
    float sp = 0.f;
    #pragma unroll
    for (int p = 0; p < PATH_DIM; p++)
      sp += path_feat[q * PATH_DIM + p] *
            (rule_init[task * PATH_DIM + p] + delta_w[task * PATH_DIM + p]);
    float lam = 1.f / (1.f + __expf(-lambda_logit[task]));
    out[q] = lam * s + (1.f - lam) * sp;
  }
}

extern "C" void kernel_launch(void* const* d_in, const int* in_sizes, int n_in,
                              void* d_out, int out_size, void* d_ws, size_t ws_size,
                              hipStream_t stream) {
  const int*   node_ids   = (const int*)d_in[0];
  const int*   edge_index = (const int*)d_in[1];
  const int*   edge_type  = (const int*)d_in[2];
  const int*   heads      = (const int*)d_in[3];
  const int*   rels       = (const int*)d_in[4];
  const int*   tails      = (const int*)d_in[5];
  const float* path_feat  = (const float*)d_in[6];
  const int*   task_idx   = (const int*)d_in[7];
  const float* entity_emb = (const float*)d_in[8];
  const float* rel_emb    = (const float*)d_in[9];
  const float* W_self     = (const float*)d_in[10];
  const float* W_rel      = (const float*)d_in[11];
  const float* delta_w    = (const float*)d_in[12];
  const float* lambda_lg  = (const float*)d_in[13];
  const float* rule_init  = (const float*)d_in[14];

  // Relation-chunk factor chosen from ws_size (host-side, deterministic).
  // Footprints: G=16 -> 281.9 MB, G=4 -> 128.3 MB, G=1 -> 89.9 MB.
  int G, glog2;
  if (ws_size >= 283000000ull)      { G = 16; glog2 = 4; }
  else if (ws_size >= 129500000ull) { G = 4;  glog2 = 2; }
  else                              { G = 1;  glog2 = 0; }
  const int MW = G * DIM + DIM;     // m row width (chunk rels + self slot)

  char* ws = (char*)d_ws;
  size_t off = 0;
  auto alloc = [&](size_t bytes) -> void* {
    void* p = ws + off;
    off = (off + bytes + 255) & ~(size_t)255;
    return p;
  };
  float* h_a   = (float*)alloc((size_t)N_NODES * DIM * 4);
  float* h_b   = (float*)alloc((size_t)N_NODES * DIM * 4);
  short* m     = (short*)alloc((size_t)N_NODES * MW * 2);
  short* wcat  = (short*)alloc((size_t)2 * DIM * KTOT * 2);
  int*   hist  = (int*)alloc((size_t)(NK + 1) * 4);
  int*   offs  = (int*)alloc((size_t)(NK + 1) * 4);
  int*   cursor= (int*)alloc((size_t)NK * 4);
  int*   bsum  = (int*)alloc((size_t)NBLK_SEG * 4);
  int*   ssrc  = (int*)alloc((size_t)E_EDGES * 4);

  hipMemsetAsync(hist, 0, (size_t)(NK + 1) * 4, stream);
  int eb = (E_EDGES + 255) / 256;
  k_hist<<<eb, 256, 0, stream>>>(edge_index, edge_type, hist);
  k_bsum<<<NBLK_SEG, 256, 0, stream>>>(hist, bsum);
  k_bscan<<<1, 1024, 0, stream>>>(bsum);
  k_offsets<<<NBLK_SEG, 256, 0, stream>>>(hist, bsum, offs, cursor);
  k_scatter<<<eb, 256, 0, stream>>>(edge_index, edge_type, cursor, ssrc);
  k_h0<<<(N_NODES * 32) / 256, 256, 0, stream>>>(node_ids, entity_emb, h_a);
  k_wcat<<<(2 * DIM * KTOT + 255) / 256, 256, 0, stream>>>(W_rel, W_self, wcat);

  const float* hin = h_a;
  float* hout = h_b;
  const int nchunk = N_REL / G;
  const int gblocks = (N_NODES + 127) / 128;
  for (int l = 0; l < 2; l++) {
    for (int c = 0; c < nchunk; c++) {
      const bool last = (c == nchunk - 1);
      k_mean<<<(N_NODES * G) / 4, 256, 0, stream>>>(hin, offs, ssrc, m, MW,
                                                    c * G, glog2);
      if (last)
        k_selfcopy<<<(N_NODES * 64) / 256, 256, 0, stream>>>(hin, m, MW, G * DIM);
      const int kc = G * DIM + (last ? DIM : 0);
      const short* wb = wcat + (size_t)l * DIM * KTOT + (size_t)c * G * DIM;
      if (c == 0 && last)
        k_gemm<false, true><<<gblocks, 256, 0, stream>>>(m, MW, wb, kc, hout);
      else if (c == 0)
        k_gemm<false, false><<<gblocks, 256, 0, stream>>>(m, MW, wb, kc, hout);
      else if (last)
        k_gemm<true, true><<<gblocks, 256, 0, stream>>>(m, MW, wb, kc, hout);
      else
        k_gemm<true, false><<<gblocks, 256, 0, stream>>>(m, MW, wb, kc, hout);
    }
    const float* tmp = hout;
    hout = (float*)hin;
    hin = tmp;
  }
  k_score<<<NQ / 4, 256, 0, stream>>>(hin, heads, rels, tails, rel_emb, path_feat,
                                      task_idx, delta_w, lambda_lg, rule_init,
                                      (float*)d_out);
}

// Round 3
// 629.657 us; speedup vs baseline: 1.2825x; 1.2825x over previous
//
#include <hip/hip_runtime.h>

#define N_NODES 50000
#define N_ENT   100000
#define N_REL   16
#define DIM     128
#define E_EDGES 600000
#define NQ      8192
#define PATH_DIM 5
#define NK      (N_NODES * N_REL)        /* 800000 (dst,rel) segments */
#define KTOT    (N_REL * DIM + DIM)      /* 2176 = 16 rel slots + self slot */
#define NBLK_SEG (NK / 256)              /* 3125 */

typedef __attribute__((ext_vector_type(8))) short short8;
typedef __attribute__((ext_vector_type(4))) float floatx4;

static __device__ __forceinline__ short f2bf(float x) {
  unsigned u = __builtin_bit_cast(unsigned, x);
  u = (u + 0x7FFFu + ((u >> 16) & 1u)) >> 16;   // RNE
  return (short)u;
}
static __device__ __forceinline__ float bf_lo(unsigned u) {
  return __builtin_bit_cast(float, u << 16);
}
static __device__ __forceinline__ float bf_hi(unsigned u) {
  return __builtin_bit_cast(float, u & 0xffff0000u);
}
static __device__ __forceinline__ unsigned pk2(float a, float b) {
  return (unsigned)(unsigned short)f2bf(a) | ((unsigned)(unsigned short)f2bf(b) << 16);
}

static __device__ __forceinline__ int wave_incl_scan(int x) {
  int lane = threadIdx.x & 63;
  #pragma unroll
  for (int off = 1; off < 64; off <<= 1) {
    int y = __shfl_up(x, off, 64);
    if (lane >= off) x += y;
  }
  return x;
}

// ---------- edge sort by (dst*16 + etype): hist -> scan -> scatter ----------
__global__ void k_hist(const int* __restrict__ ei, const int* __restrict__ et,
                       int* __restrict__ hist) {
  int e = blockIdx.x * 256 + threadIdx.x;
  if (e >= E_EDGES) return;
  int key = ei[E_EDGES + e] * N_REL + et[e];
  atomicAdd(&hist[key], 1);
}

__global__ void k_bsum(const int* __restrict__ hist, int* __restrict__ bsum) {
  int t = threadIdx.x;
  int v = hist[blockIdx.x * 256 + t];
  #pragma unroll
  for (int off = 32; off; off >>= 1) v += __shfl_xor(v, off, 64);
  __shared__ int s4[4];
  if ((t & 63) == 0) s4[t >> 6] = v;
  __syncthreads();
  if (t == 0) bsum[blockIdx.x] = s4[0] + s4[1] + s4[2] + s4[3];
}

__global__ void k_bscan(int* __restrict__ bsum) {   // 1 block, 1024 threads, 3125 items
  int t = threadIdx.x;
  int v[4], loc[4], s = 0;
  #pragma unroll
  for (int i = 0; i < 4; i++) {
    int idx = t * 4 + i;
    v[i] = (idx < NBLK_SEG) ? bsum[idx] : 0;
    loc[i] = s; s += v[i];
  }
  int incl = wave_incl_scan(s);
  __shared__ int wsum[16];
  int wid = t >> 6, lane = t & 63;
  if (lane == 63) wsum[wid] = incl;
  __syncthreads();
  if (t < 16) {
    int x = wsum[t];
    #pragma unroll
    for (int off = 1; off < 16; off <<= 1) {
      int y = __shfl_up(x, off, 64);
      if (t >= off) x += y;
    }
    wsum[t] = x;
  }
  __syncthreads();
  int wexcl = wid ? wsum[wid - 1] : 0;
  int texcl = wexcl + incl - s;
  #pragma unroll
  for (int i = 0; i < 4; i++) {
    int idx = t * 4 + i;
    if (idx < NBLK_SEG) bsum[idx] = texcl + loc[i];
  }
}

__global__ void k_offsets(const int* __restrict__ hist, const int* __restrict__ bsum,
                          int* __restrict__ offs, int* __restrict__ cursor) {
  int t = threadIdx.x;
  int g = blockIdx.x * 256 + t;
  int v = hist[g];
  int incl = wave_incl_scan(v);
  __shared__ int wsum[4];
  int wid = t >> 6, lane = t & 63;
  if (lane == 63) wsum[wid] = incl;
  __syncthreads();
  int wexcl = 0;
  for (int i = 0; i < wid; i++) wexcl += wsum[i];
  int off = bsum[blockIdx.x] + wexcl + incl - v;
  offs[g] = off;
  cursor[g] = off;
  if (g == NK - 1) offs[NK] = off + v;
}

__global__ void k_scatter(const int* __restrict__ ei, const int* __restrict__ et,
                          int* __restrict__ cursor, int* __restrict__ ssrc) {
  int e = blockIdx.x * 256 + threadIdx.x;
  if (e >= E_EDGES) return;
  int src = ei[e];
  int key = ei[E_EDGES + e] * N_REL + et[e];
  int pos = atomicAdd(&cursor[key], 1);
  ssrc[pos] = src;
}

// ---------- h0 gather (fp32 emb -> bf16 h) ----------
__global__ void k_h0(const int* __restrict__ nid, const float* __restrict__ emb,
                     unsigned* __restrict__ h) {
  int g = blockIdx.x * 256 + threadIdx.x;     // over N*32
  int n = g >> 5;
  int q = g & 31;
  float4 v = *(const float4*)(emb + (size_t)nid[n] * DIM + q * 4);
  uint2 pk;
  pk.x = pk2(v.x, v.y);
  pk.y = pk2(v.z, v.w);
  *(uint2*)(h + (size_t)n * 64 + q * 2) = pk;
}

// ---------- W_cat bf16, layout [layer][n=out 128][k=2176 (16 rel slots | self)] ----------
__global__ void k_wcat(const float* __restrict__ wrel, const float* __restrict__ wself,
                       short* __restrict__ wcat) {
  int g = blockIdx.x * 256 + threadIdx.x;
  if (g >= 2 * DIM * KTOT) return;
  int l = g / (DIM * KTOT);
  int rem = g - l * DIM * KTOT;
  int n = rem / KTOT;
  int k = rem - n * KTOT;
  float v;
  if (k < N_REL * DIM) {
    int r = k >> 7, d = k & 127;
    v = wrel[(((size_t)l * N_REL + r) * DIM + d) * DIM + n];
  } else {
    int d = k - N_REL * DIM;
    v = wself[((size_t)l * DIM + d) * DIM + n];
  }
  wcat[g] = f2bf(v);
}

// ---------- self slot copy h(bf16) -> m[:, 2048:2176] ----------
__global__ void k_selfcopy(const unsigned* __restrict__ h, short* __restrict__ m,
                           int n0, int nrows) {
  int g = blockIdx.x * 256 + threadIdx.x;   // over nrows*32
  if (g >= nrows * 32) return;
  int n = g >> 5;
  int q = g & 31;
  uint2 v = *(const uint2*)(h + (size_t)(n0 + n) * 64 + q * 2);
  *(uint2*)(m + (size_t)n * KTOT + N_REL * DIM + q * 4) = v;
}

// ---------- per-(dst,rel) mean (bf16 h in, bf16 m out): one wave per segment ----------
__global__ void k_mean(const unsigned* __restrict__ h, const int* __restrict__ offs,
                       const int* __restrict__ ssrc, short* __restrict__ m, int n0) {
  int s = (blockIdx.x * 256 + threadIdx.x) >> 6;   // local segment id, wave-uniform
  int lane = threadIdx.x & 63;
  int lrow = s >> 4;
  int r = s & 15;
  int key = (n0 + lrow) * N_REL + r;
  int start = offs[key], end = offs[key + 1];
  float s0 = 0.f, s1 = 0.f;
  for (int p = start; p < end; ++p) {
    int src = ssrc[p];
    unsigned u = h[(size_t)src * 64 + lane];
    s0 += bf_lo(u); s1 += bf_hi(u);
  }
  int cnt = end - start;
  float inv = 1.0f / (float)(cnt > 0 ? cnt : 1);
  *(unsigned*)(m + (size_t)lrow * KTOT + r * DIM + lane * 2) = pk2(s0 * inv, s1 * inv);
}

// ---------- chunk GEMM: hout = relu(m[nrows,2176] @ wb^T) bf16 out ----------
__global__ __launch_bounds__(256) void k_gemm(const short* __restrict__ m,
                                              const short* __restrict__ wb,
                                              unsigned* __restrict__ hout,  // bf16 pairs
                                              int nrows) {
  __shared__ short As[128][40];   // +8 pad: row stride 80B -> 2-way bank alias (free)
  __shared__ short Bs[128][40];   // B stored [n][k]
  int t = threadIdx.x;
  int wave = t >> 6, lane = t & 63;
  int quad = lane >> 4, rA = lane & 15;
  int row0 = blockIdx.x * 128;
  floatx4 acc[2][8];
  #pragma unroll
  for (int a = 0; a < 2; a++)
    #pragma unroll
    for (int b = 0; b < 8; b++) acc[a][b] = (floatx4)0.f;

  for (int k0 = 0; k0 < KTOT; k0 += 32) {
    __syncthreads();
    #pragma unroll
    for (int it = 0; it < 2; it++) {
      int idx = t + it * 256;
      int r = idx >> 2, q = idx & 3;
      int lr = row0 + r;
      uint4 va = (lr < nrows)
                   ? *(const uint4*)(m + (size_t)lr * KTOT + k0 + q * 8)
                   : make_uint4(0u, 0u, 0u, 0u);
      *(uint4*)&As[r][q * 8] = va;
      uint4 vb = *(const uint4*)(wb + (size_t)r * KTOT + k0 + q * 8);
      *(uint4*)&Bs[r][q * 8] = vb;
    }
    __syncthreads();
    short8 a0 = *(const short8*)&As[wave * 32 + rA][quad * 8];
    short8 a1 = *(const short8*)&As[wave * 32 + 16 + rA][quad * 8];
    #pragma unroll
    for (int nt = 0; nt < 8; nt++) {
      short8 b = *(const short8*)&Bs[nt * 16 + rA][quad * 8];
      acc[0][nt] = __builtin_amdgcn_mfma_f32_16x16x32_bf16(a0, b, acc[0][nt], 0, 0, 0);
      acc[1][nt] = __builtin_amdgcn_mfma_f32_16x16x32_bf16(a1, b, acc[1][nt], 0, 0, 0);
    }
  }
  // C: row=(lane>>4)*4+reg, col=lane&15. Pack 2 cols? cols differ by lane -> scalar
  // bf16 stores (2B), 16-lane groups hit 32B segments; acceptable (small total).
  #pragma unroll
  for (int mt = 0; mt < 2; mt++)
    #pragma unroll
    for (int nt = 0; nt < 8; nt++)
      #pragma unroll
      for (int j = 0; j < 4; j++) {
        int row = row0 + wave * 32 + mt * 16 + quad * 4 + j;
        int col = nt * 16 + rA;
        if (row < nrows) {
          float v = fmaxf(acc[mt][nt][j], 0.f);
          ((short*)hout)[(size_t)row * DIM + col] = f2bf(v);
        }
      }
}

// ---------- scoring (bf16 h) ----------
__global__ void k_score(const unsigned* __restrict__ h, const int* __restrict__ heads,
                        const int* __restrict__ rels, const int* __restrict__ tails,
                        const float* __restrict__ rel_emb, const float* __restrict__ path_feat,
                        const int* __restrict__ task_idx, const float* __restrict__ delta_w,
                        const float* __restrict__ lambda_logit, const float* __restrict__ rule_init,
                        float* __restrict__ out) {
  int q = (blockIdx.x * 256 + threadIdx.x) >> 6;
  int lane = threadIdx.x & 63;
  int hd = heads[q], tl = tails[q], rl = rels[q];
  unsigned ua = h[(size_t)hd * 64 + lane];
  unsigned uc = h[(size_t)tl * 64 + lane];
  float2 r = *(const float2*)(rel_emb + (size_t)rl * DIM + lane * 2);
  float s = bf_lo(ua) * r.x * bf_lo(uc) + bf_hi(ua) * r.y * bf_hi(uc);
  #pragma unroll
  for (int off = 32; off; off >>= 1) s += __shfl_xor(s, off, 64);
  if (lane == 0) {
    int task = task_idx[0];
    float sp = 0.f;
    #pragma unroll
    for (int p = 0; p < PATH_DIM; p++)
      sp += path_feat[q * PATH_DIM + p] *
            (rule_init[task * PATH_DIM + p] + delta_w[task * PATH_DIM + p]);
    float lam = 1.f / (1.f + __expf(-lambda_logit[task]));
    out[q] = lam * s + (1.f - lam) * sp;
  }
}

extern "C" void kernel_launch(void* const* d_in, const int* in_sizes, int n_in,
                              void* d_out, int out_size, void* d_ws, size_t ws_size,
                              hipStream_t stream) {
  const int*   node_ids   = (const int*)d_in[0];
  const int*   edge_index = (const int*)d_in[1];
  const int*   edge_type  = (const int*)d_in[2];
  const int*   heads      = (const int*)d_in[3];
  const int*   rels       = (const int*)d_in[4];
  const int*   tails      = (const int*)d_in[5];
  const float* path_feat  = (const float*)d_in[6];
  const int*   task_idx   = (const int*)d_in[7];
  const float* entity_emb = (const float*)d_in[8];
  const float* rel_emb    = (const float*)d_in[9];
  const float* W_self     = (const float*)d_in[10];
  const float* W_rel      = (const float*)d_in[11];
  const float* delta_w    = (const float*)d_in[12];
  const float* lambda_lg  = (const float*)d_in[13];
  const float* rule_init  = (const float*)d_in[14];

  char* ws = (char*)d_ws;
  size_t off = 0;
  auto alloc = [&](size_t bytes) -> void* {
    void* p = ws + off;
    off = (off + bytes + 255) & ~(size_t)255;
    return p;
  };
  // persistent buffers (h in bf16 now)
  unsigned* h_a  = (unsigned*)alloc((size_t)N_NODES * DIM * 2);
  unsigned* h_b  = (unsigned*)alloc((size_t)N_NODES * DIM * 2);
  short*    wcat = (short*)alloc((size_t)2 * DIM * KTOT * 2);
  int*      offs = (int*)alloc((size_t)(NK + 1) * 4);
  int*      ssrc = (int*)alloc((size_t)E_EDGES * 4);

  // m chunk buffer: rest of ws. hist/cursor/bsum (dead after sort) overlap m.
  size_t avail = (ws_size > off) ? (ws_size - off) : 0;
  int NCH = 10;
  if      (avail >= (size_t)N_NODES       * KTOT * 2) NCH = 1;
  else if (avail >= (size_t)(N_NODES / 2) * KTOT * 2) NCH = 2;
  else if (avail >= (size_t)(N_NODES / 4) * KTOT * 2) NCH = 4;
  else if (avail >= (size_t)(N_NODES / 5) * KTOT * 2) NCH = 5;
  else if (avail >= (size_t)(N_NODES / 8) * KTOT * 2) NCH = 8;
  const int CR = N_NODES / NCH;    // chunk rows
  short* m      = (short*)(ws + off);
  int*   hist   = (int*)m;
  int*   cursor = hist + (NK + 1);
  int*   bsum   = cursor + NK;

  hipMemsetAsync(hist, 0, (size_t)(NK + 1) * 4, stream);
  int eb = (E_EDGES + 255) / 256;
  k_hist<<<eb, 256, 0, stream>>>(edge_index, edge_type, hist);
  k_bsum<<<NBLK_SEG, 256, 0, stream>>>(hist, bsum);
  k_bscan<<<1, 1024, 0, stream>>>(bsum);
  k_offsets<<<NBLK_SEG, 256, 0, stream>>>(hist, bsum, offs, cursor);
  k_scatter<<<eb, 256, 0, stream>>>(edge_index, edge_type, cursor, ssrc);
  k_h0<<<(N_NODES * 32) / 256, 256, 0, stream>>>(node_ids, entity_emb, h_a);
  k_wcat<<<(2 * DIM * KTOT + 255) / 256, 256, 0, stream>>>(W_rel, W_self, wcat);

  const unsigned* hin = h_a;
  unsigned* hout = h_b;
  for (int l = 0; l < 2; l++) {
    const short* wb = wcat + (size_t)l * DIM * KTOT;
    for (int c = 0; c < NCH; c++) {
      int n0 = c * CR;
      k_mean<<<CR * 4, 256, 0, stream>>>(hin, offs, ssrc, m, n0);
      k_selfcopy<<<(CR * 32 + 255) / 256, 256, 0, stream>>>(hin, m, n0, CR);
      k_gemm<<<(CR + 127) / 128, 256, 0, stream>>>(m, wb, hout + (size_t)n0 * 64, CR);
    }
    const unsigned* tmp = hout;
    hout = (unsigned*)hin;
    hin = tmp;
  }
  k_score<<<NQ / 4, 256, 0, stream>>>(hin, heads, rels, tails, rel_emb, path_feat,
                                      task_idx, delta_w, lambda_lg, rule_init,
                                      (float*)d_out);
}